// Round 1
// baseline (1994.829 us; speedup 1.0000x reference)
//
#include <hip/hip_runtime.h>
#include <math.h>

#define NN 20000
#define NE 320000

__device__ __forceinline__ float frelu(float x){ return fmaxf(x, 0.0f); }

// Recompute geometry + edge embedding (cheap vs the big MLPs; keeps ws small).
// Fills eemb[16] and sh1[3].
__device__ __forceinline__ void edge_embed(
    int e, int s, int d,
    const float* __restrict__ pos,
    const float* __restrict__ edge_bond,
    const float* __restrict__ em_w1, const float* __restrict__ em_b1,
    const float* __restrict__ em_w2, const float* __restrict__ em_b2,
    float* eemb, float* sh1)
{
    float vx = pos[d*3+0] - pos[s*3+0];
    float vy = pos[d*3+1] - pos[s*3+1];
    float vz = pos[d*3+2] - pos[s*3+2];
    float d2 = vx*vx + vy*vy + vz*vz + 1e-12f;
    float dist = sqrtf(d2);
    float inv = 1.0f / (dist + 1e-8f);
    const float SQ3 = 1.7320508075688772f;
    sh1[0] = SQ3 * vx * inv;
    sh1[1] = SQ3 * vy * inv;
    sh1[2] = SQ3 * vz * inv;

    float ein[42];
    #pragma unroll
    for (int t = 0; t < 10; ++t) ein[t] = edge_bond[e*10 + t];
    const float coeff = -19.22f;            // -0.5 / (5/31)^2
    const float step  = 5.0f / 31.0f;
    #pragma unroll
    for (int k = 0; k < 32; ++k) {
        float dd = dist - step * (float)k;
        ein[10+k] = __expf(coeff * dd * dd);
    }

    float t1[16];
    #pragma unroll
    for (int j = 0; j < 16; ++j) t1[j] = em_b1[j];
    #pragma unroll
    for (int t = 0; t < 42; ++t) {
        float v = ein[t];
        #pragma unroll
        for (int j = 0; j < 16; ++j) t1[j] += v * em_w1[t*16 + j];
    }
    #pragma unroll
    for (int j = 0; j < 16; ++j) t1[j] = frelu(t1[j]);

    #pragma unroll
    for (int j = 0; j < 16; ++j) eemb[j] = em_b2[j];
    #pragma unroll
    for (int t = 0; t < 16; ++t) {
        float v = t1[t];
        #pragma unroll
        for (int j = 0; j < 16; ++j) eemb[j] += v * em_w2[t*16 + j];
    }
}

__global__ __launch_bounds__(256)
void k_node_feat(const int* __restrict__ x_cat, const float* __restrict__ x_scalar,
                 const float* __restrict__ emb, const float* __restrict__ node_w,
                 const float* __restrict__ node_b, float* __restrict__ node0)
{
    int n = blockIdx.x * 256 + threadIdx.x;
    if (n >= NN) return;
    float acc[16];
    #pragma unroll
    for (int k = 0; k < 16; ++k) acc[k] = node_b[k];
    #pragma unroll
    for (int c = 0; c < 10; ++c) {
        int idx = x_cat[n*10 + c];
        const float4* row = reinterpret_cast<const float4*>(emb + (c*119 + idx)*16);
        #pragma unroll
        for (int k = 0; k < 4; ++k) {
            float4 q = row[k];
            acc[4*k+0] += q.x; acc[4*k+1] += q.y; acc[4*k+2] += q.z; acc[4*k+3] += q.w;
        }
    }
    #pragma unroll
    for (int t = 0; t < 32; ++t) {
        float xs = x_scalar[n*32 + t];
        #pragma unroll
        for (int k = 0; k < 16; ++k) acc[k] += xs * node_w[t*16 + k];
    }
    #pragma unroll
    for (int k = 0; k < 16; ++k) node0[n*16 + k] = acc[k];
}

__global__ __launch_bounds__(256)
void k_edge_l1(const int* __restrict__ ei, const float* __restrict__ pos,
               const float* __restrict__ edge_bond,
               const float* __restrict__ em_w1, const float* __restrict__ em_b1,
               const float* __restrict__ em_w2, const float* __restrict__ em_b2,
               const float* __restrict__ w1, const float* __restrict__ b1,
               const float* __restrict__ w2, const float* __restrict__ b2,
               const float* __restrict__ node0,
               float* __restrict__ accum, float* __restrict__ cnt)
{
    int e = blockIdx.x * 256 + threadIdx.x;
    if (e >= NE) return;
    int s = ei[e], d = ei[NE + e];

    float ea[48];
    float sh1[3];
    edge_embed(e, s, d, pos, edge_bond, em_w1, em_b1, em_w2, em_b2, ea, sh1);
    {
        const float4* rs = reinterpret_cast<const float4*>(node0 + s*16);
        const float4* rd = reinterpret_cast<const float4*>(node0 + d*16);
        #pragma unroll
        for (int k = 0; k < 4; ++k) {
            float4 q = rs[k];
            ea[16+4*k] = q.x; ea[17+4*k] = q.y; ea[18+4*k] = q.z; ea[19+4*k] = q.w;
            float4 r = rd[k];
            ea[32+4*k] = r.x; ea[33+4*k] = r.y; ea[34+4*k] = r.z; ea[35+4*k] = r.w;
        }
    }

    // h = relu(ea @ W1 + b1)
    float h[48];
    #pragma unroll
    for (int j = 0; j < 48; ++j) h[j] = b1[j];
    #pragma unroll
    for (int t = 0; t < 48; ++t) {
        float v = ea[t];
        #pragma unroll
        for (int j = 0; j < 48; ++j) h[j] += v * w1[t*48 + j];
    }
    #pragma unroll
    for (int j = 0; j < 48; ++j) h[j] = frelu(h[j]);

    // out0[k] = sum_u s_u * (b2 + h@W2)[u*16+k]
    float out0[16];
    #pragma unroll
    for (int k = 0; k < 16; ++k) out0[k] = 0.0f;
    for (int u = 0; u < 16; ++u) {             // runtime loop: s_u re-read via L1
        float wk[16];
        #pragma unroll
        for (int k = 0; k < 16; ++k) wk[k] = b2[u*16 + k];
        #pragma unroll
        for (int j = 0; j < 48; ++j) {
            float hv = h[j];
            #pragma unroll
            for (int k = 0; k < 16; ++k) wk[k] += hv * w2[j*320 + u*16 + k];
        }
        float su = node0[d*16 + u];
        #pragma unroll
        for (int k = 0; k < 16; ++k) out0[k] += su * wk[k];
    }

    float ob[4] = {0.f, 0.f, 0.f, 0.f};
    for (int u = 0; u < 16; ++u) {
        float wq[4];
        #pragma unroll
        for (int q = 0; q < 4; ++q) wq[q] = b2[256 + u*4 + q];
        #pragma unroll
        for (int j = 0; j < 48; ++j) {
            float hv = h[j];
            #pragma unroll
            for (int q = 0; q < 4; ++q) wq[q] += hv * w2[j*320 + 256 + u*4 + q];
        }
        float su = node0[d*16 + u];
        #pragma unroll
        for (int q = 0; q < 4; ++q) ob[q] += su * wq[q];
    }

    const float a = 0.25f;                     // 1/sqrt(16)
    float* out = accum + (size_t)s * 28;
    #pragma unroll
    for (int k = 0; k < 16; ++k) atomicAdd(out + k, out0[k] * a);
    #pragma unroll
    for (int q = 0; q < 4; ++q)
        #pragma unroll
        for (int i = 0; i < 3; ++i)
            atomicAdd(out + 16 + q*3 + i, ob[q] * a * sh1[i]);
    atomicAdd(cnt + s, 1.0f);
}

__global__ __launch_bounds__(256)
void k_edge_l2(const int* __restrict__ ei, const float* __restrict__ pos,
               const float* __restrict__ edge_bond,
               const float* __restrict__ em_w1, const float* __restrict__ em_b1,
               const float* __restrict__ em_w2, const float* __restrict__ em_b2,
               const float* __restrict__ w1, const float* __restrict__ b1,
               const float* __restrict__ w2, const float* __restrict__ b2,
               const float* __restrict__ node1,
               float* __restrict__ accum2)
{
    int e = blockIdx.x * 256 + threadIdx.x;
    if (e >= NE) return;
    int s = ei[e], d = ei[NE + e];

    float ea[48];
    float sh1[3];
    edge_embed(e, s, d, pos, edge_bond, em_w1, em_b1, em_w2, em_b2, ea, sh1);

    float v[12];
    {
        const float4* rs = reinterpret_cast<const float4*>(node1 + (size_t)s*28);
        const float4* rd = reinterpret_cast<const float4*>(node1 + (size_t)d*28);
        #pragma unroll
        for (int k = 0; k < 4; ++k) {
            float4 q = rs[k];
            ea[16+4*k] = q.x; ea[17+4*k] = q.y; ea[18+4*k] = q.z; ea[19+4*k] = q.w;
            float4 r = rd[k];
            ea[32+4*k] = r.x; ea[33+4*k] = r.y; ea[34+4*k] = r.z; ea[35+4*k] = r.w;
        }
        #pragma unroll
        for (int k = 0; k < 3; ++k) {
            float4 r = rd[4+k];
            v[4*k+0] = r.x; v[4*k+1] = r.y; v[4*k+2] = r.z; v[4*k+3] = r.w;
        }
    }

    float vdot[4], crs[12];
    #pragma unroll
    for (int u = 0; u < 4; ++u) {
        vdot[u] = v[u*3+0]*sh1[0] + v[u*3+1]*sh1[1] + v[u*3+2]*sh1[2];
        crs[u*3+0] = v[u*3+1]*sh1[2] - v[u*3+2]*sh1[1];
        crs[u*3+1] = v[u*3+2]*sh1[0] - v[u*3+0]*sh1[2];
        crs[u*3+2] = v[u*3+0]*sh1[1] - v[u*3+1]*sh1[0];
    }

    float h[48];
    #pragma unroll
    for (int j = 0; j < 48; ++j) h[j] = b1[j];
    #pragma unroll
    for (int t = 0; t < 48; ++t) {
        float vv = ea[t];
        #pragma unroll
        for (int j = 0; j < 48; ++j) h[j] += vv * w1[t*48 + j];
    }
    #pragma unroll
    for (int j = 0; j < 48; ++j) h[j] = frelu(h[j]);

    // out0: wa with s, wb with vdot/sqrt3
    float out0[16];
    #pragma unroll
    for (int k = 0; k < 16; ++k) out0[k] = 0.0f;
    for (int u = 0; u < 16; ++u) {           // wa
        float wk[16];
        #pragma unroll
        for (int k = 0; k < 16; ++k) wk[k] = b2[u*16 + k];
        #pragma unroll
        for (int j = 0; j < 48; ++j) {
            float hv = h[j];
            #pragma unroll
            for (int k = 0; k < 16; ++k) wk[k] += hv * w2[j*416 + u*16 + k];
        }
        float su = node1[(size_t)d*28 + u];
        #pragma unroll
        for (int k = 0; k < 16; ++k) out0[k] += su * wk[k];
    }
    const float INV_SQ3 = 0.5773502691896258f;
    #pragma unroll
    for (int u = 0; u < 4; ++u) {            // wb (vdot static -> unrolled)
        float wk[16];
        #pragma unroll
        for (int k = 0; k < 16; ++k) wk[k] = b2[256 + u*16 + k];
        #pragma unroll
        for (int j = 0; j < 48; ++j) {
            float hv = h[j];
            #pragma unroll
            for (int k = 0; k < 16; ++k) wk[k] += hv * w2[j*416 + 256 + u*16 + k];
        }
        float vu = vdot[u] * INV_SQ3;
        #pragma unroll
        for (int k = 0; k < 16; ++k) out0[k] += vu * wk[k];
    }

    // wc: outc[q] = sum_u wc[u,q] * s_u
    float outc[4] = {0.f, 0.f, 0.f, 0.f};
    for (int u = 0; u < 16; ++u) {
        float wq[4];
        #pragma unroll
        for (int q = 0; q < 4; ++q) wq[q] = b2[320 + u*4 + q];
        #pragma unroll
        for (int j = 0; j < 48; ++j) {
            float hv = h[j];
            #pragma unroll
            for (int q = 0; q < 4; ++q) wq[q] += hv * w2[j*416 + 320 + u*4 + q];
        }
        float su = node1[(size_t)d*28 + u];
        #pragma unroll
        for (int q = 0; q < 4; ++q) outc[q] += su * wq[q];
    }

    // wd: o1o[q,i] += wd[u,q]*v[u,i]
    float o1o[12];
    #pragma unroll
    for (int t = 0; t < 12; ++t) o1o[t] = 0.0f;
    #pragma unroll
    for (int u = 0; u < 4; ++u) {
        float wq[4];
        #pragma unroll
        for (int q = 0; q < 4; ++q) wq[q] = b2[384 + u*4 + q];
        #pragma unroll
        for (int j = 0; j < 48; ++j) {
            float hv = h[j];
            #pragma unroll
            for (int q = 0; q < 4; ++q) wq[q] += hv * w2[j*416 + 384 + u*4 + q];
        }
        #pragma unroll
        for (int q = 0; q < 4; ++q) {
            o1o[q*3+0] += wq[q] * v[u*3+0];
            o1o[q*3+1] += wq[q] * v[u*3+1];
            o1o[q*3+2] += wq[q] * v[u*3+2];
        }
    }

    // we: o1e[q,i] += we[u,q]*crs[u,i]
    float o1e[12];
    #pragma unroll
    for (int t = 0; t < 12; ++t) o1e[t] = 0.0f;
    #pragma unroll
    for (int u = 0; u < 4; ++u) {
        float wq[4];
        #pragma unroll
        for (int q = 0; q < 4; ++q) wq[q] = b2[400 + u*4 + q];
        #pragma unroll
        for (int j = 0; j < 48; ++j) {
            float hv = h[j];
            #pragma unroll
            for (int q = 0; q < 4; ++q) wq[q] += hv * w2[j*416 + 400 + u*4 + q];
        }
        #pragma unroll
        for (int q = 0; q < 4; ++q) {
            o1e[q*3+0] += wq[q] * crs[u*3+0];
            o1e[q*3+1] += wq[q] * crs[u*3+1];
            o1e[q*3+2] += wq[q] * crs[u*3+2];
        }
    }

    const float A0 = 0.22360679774997896f;   // 1/sqrt(20)
    const float AE = 0.3535533905932738f;    // 0.5/sqrt(2)
    float* out = accum2 + (size_t)s * 40;
    #pragma unroll
    for (int k = 0; k < 16; ++k) atomicAdd(out + k, out0[k] * A0);
    #pragma unroll
    for (int q = 0; q < 4; ++q)
        #pragma unroll
        for (int i = 0; i < 3; ++i)
            atomicAdd(out + 16 + q*3 + i, (outc[q]*sh1[i] + o1o[q*3+i]) * A0);
    #pragma unroll
    for (int t = 0; t < 12; ++t) atomicAdd(out + 28 + t, o1e[t] * AE);
}

__global__ __launch_bounds__(256)
void k_div(const float* in, float* out, const float* __restrict__ cnt, int cols, int total)
{
    int i = blockIdx.x * 256 + threadIdx.x;
    if (i >= total) return;
    int n = i / cols;
    out[i] = in[i] / fmaxf(cnt[n], 1.0f);
}

extern "C" void kernel_launch(void* const* d_in, const int* in_sizes, int n_in,
                              void* d_out, int out_size, void* d_ws, size_t ws_size,
                              hipStream_t stream) {
    const int*   x_cat     = (const int*)  d_in[0];
    const float* x_scalar  = (const float*)d_in[1];
    const float* pos       = (const float*)d_in[2];
    const int*   ei        = (const int*)  d_in[3];
    const float* edge_bond = (const float*)d_in[4];
    const float* emb       = (const float*)d_in[5];
    const float* node_w    = (const float*)d_in[6];
    const float* node_b    = (const float*)d_in[7];
    const float* em_w1     = (const float*)d_in[8];
    const float* em_b1     = (const float*)d_in[9];
    const float* em_w2     = (const float*)d_in[10];
    const float* em_b2     = (const float*)d_in[11];
    const float* c1_w1     = (const float*)d_in[12];
    const float* c1_b1     = (const float*)d_in[13];
    const float* c1_w2     = (const float*)d_in[14];
    const float* c1_b2     = (const float*)d_in[15];
    const float* c2_w1     = (const float*)d_in[16];
    const float* c2_b1     = (const float*)d_in[17];
    const float* c2_w2     = (const float*)d_in[18];
    const float* c2_b2     = (const float*)d_in[19];

    float* ws     = (float*)d_ws;
    float* node0  = ws;                  // NN*16 = 320000
    float* accum1 = ws + 320000;         // NN*28 = 560000 (becomes node1 in place)
    float* accum2 = ws + 880000;         // NN*40 = 800000
    float* cnt    = ws + 1680000;        // NN    = 20000

    hipMemsetAsync(accum1, 0, (size_t)(560000 + 800000 + 20000) * sizeof(float), stream);

    k_node_feat<<<(NN + 255) / 256, 256, 0, stream>>>(
        x_cat, x_scalar, emb, node_w, node_b, node0);

    k_edge_l1<<<(NE + 255) / 256, 256, 0, stream>>>(
        ei, pos, edge_bond, em_w1, em_b1, em_w2, em_b2,
        c1_w1, c1_b1, c1_w2, c1_b2, node0, accum1, cnt);

    k_div<<<(560000 + 255) / 256, 256, 0, stream>>>(accum1, accum1, cnt, 28, 560000);

    k_edge_l2<<<(NE + 255) / 256, 256, 0, stream>>>(
        ei, pos, edge_bond, em_w1, em_b1, em_w2, em_b2,
        c2_w1, c2_b1, c2_w2, c2_b2, accum1, accum2);

    k_div<<<(800000 + 255) / 256, 256, 0, stream>>>(accum2, (float*)d_out, cnt, 40, 800000);
}